// Round 4
// baseline (707.027 us; speedup 1.0000x reference)
//
#include <hip/hip_runtime.h>

// Problem constants
#define BATCH 64
#define SEQ   577
#define CDIM  768
#define NH    12
#define HD    64
#define MROWS (BATCH * SEQ)      // 36928
#define KDIM  768
#define QKV_N (3 * CDIM)         // 2304
#define NPAD  640                // vt row length (multiple of 64)
#define TQ    128                // flash q-tile rows per block
#define PS    40                 // sP row stride (u16)
#define OS    72                 // O-repack row stride (u16)
#define DEAD_M 18464             // first dead row: b>=32  (32*577)

typedef short bf16x8 __attribute__((ext_vector_type(8)));
typedef float f32x4  __attribute__((ext_vector_type(4)));

__device__ __forceinline__ unsigned short f2bf(float f) {
  unsigned int u = __float_as_uint(f);
  u += 0x7fffu + ((u >> 16) & 1u);   // round-to-nearest-even
  return (unsigned short)(u >> 16);
}

__device__ __forceinline__ void async_ld16(const unsigned short* g, unsigned short* l) {
  __builtin_amdgcn_global_load_lds((const __attribute__((address_space(1))) void*)g,
                                   (__attribute__((address_space(3))) void*)l, 16, 0, 0);
}

// bijective XCD-chunked block swizzle (m204)
__device__ __forceinline__ int xcd_swz(int id, int nwg) {
  int q = nwg >> 3, r = nwg & 7;
  int xcd = id & 7, lin = id >> 3;
  int base = (xcd < r) ? xcd * (q + 1) : r * (q + 1) + (xcd - r) * q;
  return base + lin;
}

// ---------------- fp32 -> bf16 conversion ----------------
__global__ __launch_bounds__(256) void cvt_bf16(const float* __restrict__ in,
                                                unsigned short* __restrict__ out, int n4) {
  int i = blockIdx.x * 256 + threadIdx.x;
  if (i < n4) {
    float4 f = ((const float4*)in)[i];
    ushort4 o = make_ushort4(f2bf(f.x), f2bf(f.y), f2bf(f.z), f2bf(f.w));
    ((ushort4*)out)[i] = o;
  }
}

// ============================================================================
// 256x256x(BK=64) GEMM main loop with cross-half REGISTER pipelining.
//   Steady state per K-tile t (buf d = t&1):
//     [read half1(t) -> Rb  || MFMA(Ra = half0(t))]        <- LDS pipe || MFMA pipe
//     vmcnt(0); barrier                                    <- stage(t+1) landed
//     [read half0(t+1) -> Ra || stage(t+2) || MFMA(Rb)]
//   sched_barrier(0) pins read-issue before each MFMA cluster; the lgkm wait
//   before a cluster counts only the 12 newer in-flight reads.
//   Overwrite safety: reads of a buffer are issued >=1 MFMA cluster before the
//   barrier; the overwriting global_load_lds data lands >=200cyc after it.
//   LDS swizzle (16B chunk ^= (row>>1)&3): verified conflict-free (r1: BANK=0).
// ============================================================================
__device__ __forceinline__ void gemm256_loop(
    const unsigned short* __restrict__ A,
    const unsigned short* __restrict__ Bm,
    unsigned short* sL,           // 65536 u16 = 128 KiB
    int row0, int col0,
    f32x4 (&acc)[8][4]) {
  const int tid = threadIdx.x;
  const int w = tid >> 6, lane = tid & 63;
  const int quad = lane >> 4, l16 = lane & 15;
  const int wm = w >> 2, wn = w & 3;

  // ---- staging source pointers (row-invariant across K) ----
  const int rl0 = w * 32 + (lane >> 2);        // LDS row for instr c=0 (0..255)
  const int rl1 = rl0 + 16;                    // instr c=1 (same (row>>1)&3)
  const int ch = (((lane & 3) ^ ((lane >> 3) & 3)) << 3);  // swizzled k-chunk (elems)
  int ga0 = row0 + rl0; if (ga0 >= MROWS) ga0 = MROWS - 1;
  int ga1 = row0 + rl1; if (ga1 >= MROWS) ga1 = MROWS - 1;
  const unsigned short* aSrc0 = A + (size_t)ga0 * KDIM + ch;
  const unsigned short* aSrc1 = A + (size_t)ga1 * KDIM + ch;
  const unsigned short* bSrc0 = Bm + (size_t)(col0 + rl0) * KDIM + ch;
  const unsigned short* bSrc1 = Bm + (size_t)(col0 + rl1) * KDIM + ch;
  const int sdst = w * 1024;                   // u16, wave-uniform LDS stage base

  // ---- ds_read bases (u16); swizzle term constant per lane ----
  const int swz = ((quad ^ ((l16 >> 1) & 3)) << 3);
  const int arow = (wm * 128 + l16) * 32 + swz;            // within A half
  const int brow = (wn * 64 + l16) * 32 + swz + 16384;     // B base folded

  // 8 loads per K-tile: A(ks0), B(ks0), A(ks1), B(ks1)
#define STAGE_ALL(off, kt) do {                                                  \
    async_ld16(aSrc0 + (kt) * 64,      sL + (off) + sdst);                       \
    async_ld16(aSrc1 + (kt) * 64,      sL + (off) + sdst + 512);                 \
    async_ld16(bSrc0 + (kt) * 64,      sL + (off) + 16384 + sdst);               \
    async_ld16(bSrc1 + (kt) * 64,      sL + (off) + 16384 + sdst + 512);         \
    async_ld16(aSrc0 + (kt) * 64 + 32, sL + (off) + 8192 + sdst);                \
    async_ld16(aSrc1 + (kt) * 64 + 32, sL + (off) + 8192 + sdst + 512);          \
    async_ld16(bSrc0 + (kt) * 64 + 32, sL + (off) + 24576 + sdst);               \
    async_ld16(bSrc1 + (kt) * 64 + 32, sL + (off) + 24576 + sdst + 512);         \
  } while (0)

  // prologue: tile0 -> buf0, wait, preload Ra = half0(tile0), stage tile1 -> buf1
  STAGE_ALL(0, 0);
  asm volatile("s_waitcnt vmcnt(0)" ::: "memory");
  __builtin_amdgcn_s_barrier();

  bf16x8 afa[8], bva[4], afb[8], bvb[4];
  #pragma unroll
  for (int i = 0; i < 8; ++i) afa[i] = *(const bf16x8*)&sL[arow + i * 512];
  #pragma unroll
  for (int j = 0; j < 4; ++j) bva[j] = *(const bf16x8*)&sL[brow + j * 512];
  STAGE_ALL(32768, 1);

  #pragma unroll 2
  for (int t = 0; t < 12; ++t) {
    const int d = (t & 1) << 15;
    const int nd = d ^ 32768;
    // ---- read half1(t) -> Rb, overlapped with MFMA(Ra) ----
    #pragma unroll
    for (int i = 0; i < 8; ++i) afb[i] = *(const bf16x8*)&sL[d + 8192 + arow + i * 512];
    #pragma unroll
    for (int j = 0; j < 4; ++j) bvb[j] = *(const bf16x8*)&sL[d + 8192 + brow + j * 512];
    __builtin_amdgcn_sched_barrier(0);
    __builtin_amdgcn_s_setprio(1);
    #pragma unroll
    for (int i = 0; i < 8; ++i)
      #pragma unroll
      for (int j = 0; j < 4; ++j)
        acc[i][j] = __builtin_amdgcn_mfma_f32_16x16x32_bf16(afa[i], bva[j], acc[i][j], 0, 0, 0);
    __builtin_amdgcn_s_setprio(0);
    __builtin_amdgcn_sched_barrier(0);
    if (t < 11) {
      asm volatile("s_waitcnt vmcnt(0)" ::: "memory");   // stage(t+1) landed in buf nd
      __builtin_amdgcn_s_barrier();
      // ---- read half0(t+1) -> Ra + stage(t+2), overlapped with MFMA(Rb) ----
      #pragma unroll
      for (int i = 0; i < 8; ++i) afa[i] = *(const bf16x8*)&sL[nd + arow + i * 512];
      #pragma unroll
      for (int j = 0; j < 4; ++j) bva[j] = *(const bf16x8*)&sL[nd + brow + j * 512];
      if (t < 10) STAGE_ALL(d, t + 2);
      __builtin_amdgcn_sched_barrier(0);
    }
    __builtin_amdgcn_s_setprio(1);
    #pragma unroll
    for (int i = 0; i < 8; ++i)
      #pragma unroll
      for (int j = 0; j < 4; ++j)
        acc[i][j] = __builtin_amdgcn_mfma_f32_16x16x32_bf16(afb[i], bvb[j], acc[i][j], 0, 0, 0);
    __builtin_amdgcn_s_setprio(0);
    __builtin_amdgcn_sched_barrier(0);
  }
#undef STAGE_ALL
}

// ---------------- QKV GEMM: [MROWS,768] x [2304,768]^T, scatter to q/k/v bf16 ----------
__global__ __launch_bounds__(512, 2) void gemm_qkv(
    const unsigned short* __restrict__ A,
    const unsigned short* __restrict__ Bm,
    unsigned short* __restrict__ qb,
    unsigned short* __restrict__ kb,
    unsigned short* __restrict__ vb) {
  const int wg = xcd_swz(blockIdx.x, 145 * 9);
  const int mt = wg / 9, nt = wg - mt * 9;
  const int row0 = mt * 256, col0 = nt * 256;
  // fully-dead tile: all rows b>=32 and all 4 col-waves h>=6  (col0%768==512)
  if (row0 >= DEAD_M && (col0 % CDIM) == 512) return;

  __shared__ unsigned short sL[65536];
  f32x4 acc[8][4] = {};
  gemm256_loop(A, Bm, sL, row0, col0, acc);

  // loop has no trailing barrier; epilogue reuses sL -> sync first
  __builtin_amdgcn_s_barrier();

  const int tid = threadIdx.x;
  const int w = tid >> 6, lane = tid & 63;
  const int quad = lane >> 4, l16 = lane & 15;
  const int wm = w >> 2, wn = w & 3;

  const int wcol = col0 + wn * 64;             // 64-aligned -> single (three, h)
  const int three = wcol / CDIM;
  const int rem = wcol - three * CDIM;
  const int h = rem >> 6;
  unsigned short* dst = (three == 0) ? qb : (three == 1) ? kb : vb;
  const float sc = (three == 0) ? 0.180336878f : 1.0f;  // 0.125 * log2(e)
  if ((row0 + wm * 128) >= DEAD_M && h >= 6) return;    // dead wave: skip stores

  // repack: wave-private 16KB region, XOR-swizzled (slot ^= row&7) -> no bank conflicts
  unsigned short* so = sL + w * 8192;
  #pragma unroll
  for (int mf = 0; mf < 8; ++mf)
    #pragma unroll
    for (int nf = 0; nf < 4; ++nf)
      #pragma unroll
      for (int r = 0; r < 4; ++r) {
        int rr = mf * 16 + quad * 4 + r;       // 0..127 (wave-local row)
        so[rr * 64 + (((nf * 2 + (l16 >> 3)) ^ (rr & 7)) << 3) + (l16 & 7)] =
            f2bf(acc[mf][nf][r] * sc);
      }
  #pragma unroll
  for (int it = 0; it < 16; ++it) {
    int c = it * 64 + lane;                    // 1024 int4 chunks per wave
    int rr = c >> 3, s8 = c & 7;
    int m = row0 + wm * 128 + rr;
    if (m < MROWS) {
      int b = m / SEQ, n = m - b * SEQ;
      *(int4*)&dst[((((size_t)b * NH + h) * SEQ + n) << 6) + s8 * 8] =
          *(const int4*)&so[rr * 64 + ((s8 ^ (rr & 7)) << 3)];
    }
  }
}

// ---------------- V transpose: v[bh][n][64] -> vt[bh][64][NPAD], zero pads ----------------
__global__ __launch_bounds__(512) void transpose_v(
    const unsigned short* __restrict__ v,
    unsigned short* __restrict__ vt) {
  const int bh = blockIdx.y;
  const int b = bh / NH, h = bh - b * NH;
  if (b >= 32 && h >= 6) return;
  const int t = blockIdx.x;               // 0..9
  const int tid = threadIdx.x;
  const int w = tid >> 6, lane = tid & 63; // w = d8 index 0..7
  int n = t * 64 + lane;
  bf16x8 vv = {};
  if (n < SEQ)
    vv = *(const bf16x8*)&v[(size_t)bh * (SEQ * HD) + n * HD + w * 8];
  unsigned short* dst = vt + (size_t)bh * (HD * NPAD) + (w * 8) * NPAD + t * 64 + lane;
  #pragma unroll
  for (int j = 0; j < 8; j++)
    dst[j * NPAD] = ((const unsigned short*)&vv)[j];
}

// ---------------- Flash attention (no-max softmax, MFMA row-sum) ----------------
// sK/sVt XOR-swizzled (chunk ^= (row>>1)&3): conflict-free ds_read_b128.
__global__ __launch_bounds__(256, 4) void flash_attn(
    const unsigned short* __restrict__ q,   // pre-scaled by 0.125*log2e
    const unsigned short* __restrict__ k,
    const unsigned short* __restrict__ vt,  // [BH][64][NPAD], zero-padded
    unsigned short* __restrict__ attn) {    // [B, N, C] bf16
  const int id = blockIdx.x;
  const int bh8 = id / 40;
  const int rem = id - bh8 * 40;
  const int qt = rem >> 3;
  const int bh = bh8 * 8 + (rem & 7);
  const int b = bh / NH, h = bh - b * NH;
  const int tid = threadIdx.x;
  const int w = tid >> 6, lane = tid & 63;
  const int quad = lane >> 4, l16 = lane & 15;

  if (b >= 32 && h >= 6) {
    for (int it = tid; it < TQ * 8; it += 256) {
      int r = it >> 3, c8 = (it & 7) * 8;
      int n = qt * TQ + r;
      if (n < SEQ)
        *(int4*)&attn[(b * SEQ + n) * CDIM + h * 64 + c8] = make_int4(0, 0, 0, 0);
    }
    return;
  }

  __shared__ unsigned short sK[2 * 64 * 32];    // [d-half][kv][32] (chunk-swizzled)
  __shared__ unsigned short sVt[2 * 64 * 32];   // [kv-half][d][32] (chunk-swizzled)
  __shared__ unsigned short sP[4][64 * PS];     // [wave][(g*2+hf)*16+row][PS]

  const unsigned short* qbase = q + (size_t)bh * (SEQ * HD);
  const unsigned short* kbase = k + (size_t)bh * (SEQ * HD);
  const unsigned short* vtbase = vt + (size_t)bh * (HD * NPAD);

  const int fsw = ((quad ^ ((l16 >> 1) & 3)) << 3);  // read-side swizzled chunk (u16)

  bf16x8 aq[2][2];
  #pragma unroll
  for (int g = 0; g < 2; g++) {
    int qr = qt * TQ + w * 32 + g * 16 + l16;
    if (qr > SEQ - 1) qr = SEQ - 1;
    aq[g][0] = *(const bf16x8*)&qbase[qr * HD + quad * 8];
    aq[g][1] = *(const bf16x8*)&qbase[qr * HD + 32 + quad * 8];
  }

  f32x4 oacc[2][4] = {};
  f32x4 lacc[2] = {};   // row-sum accumulator via ones-fragment MFMA

  const short ONE = (short)0x3F80;  // bf16 1.0

  for (int t = 0; t < 10; t++) {
    __syncthreads();
    #pragma unroll
    for (int c = 0; c < 2; c++) {
      int rI = tid >> 2;
      int c4s = (tid & 3) ^ ((tid >> 3) & 3);   // source chunk pre-swizzle
      int base = c * 2048 + (tid & ~63) * 8;
      int kr = t * 64 + rI; if (kr > SEQ - 1) kr = SEQ - 1;
      async_ld16(kbase + kr * HD + c * 32 + c4s * 8, sK + base);
      async_ld16(vtbase + rI * NPAD + t * 64 + c * 32 + c4s * 8, sVt + base);
    }
    __syncthreads();

    bf16x8 bk[4][2];
    #pragma unroll
    for (int nt = 0; nt < 4; nt++) {
      bk[nt][0] = *(const bf16x8*)&sK[0 * 2048 + (nt * 16 + l16) * 32 + fsw];
      bk[nt][1] = *(const bf16x8*)&sK[1 * 2048 + (nt * 16 + l16) * 32 + fsw];
    }

    // ones B-fragment: B[n][k]=1 for valid kv, else 0
    bf16x8 ones0, ones1;
    if (t < 9) {
      #pragma unroll
      for (int j = 0; j < 8; j++) { ones0[j] = ONE; ones1[j] = ONE; }
    } else {
      bf16x8 z = {};
      ones0 = z; ones1 = z;
      ones0[0] = (quad == 0) ? ONE : (short)0;   // only kv==576 valid
    }

    #pragma unroll
    for (int g = 0; g < 2; g++) {
      f32x4 s[4];
      #pragma unroll
      for (int nt = 0; nt < 4; nt++) {
        f32x4 z = {};
        z = __builtin_amdgcn_mfma_f32_16x16x32_bf16(aq[g][0], bk[nt][0], z, 0, 0, 0);
        z = __builtin_amdgcn_mfma_f32_16x16x32_bf16(aq[g][1], bk[nt][1], z, 0, 0, 0);
        s[nt] = z;
      }
      #pragma unroll
      for (int nt = 0; nt < 4; nt++)
        #pragma unroll
        for (int r = 0; r < 4; r++)
          sP[w][((g * 2 + (nt >> 1)) * 16 + quad * 4 + r) * PS + (nt & 1) * 16 + l16] =
              f2bf(__builtin_exp2f(s[nt][r]));
    }

    // PV + row-sum (sP wave-private; same-wave DS ordering suffices, no barrier)
    #pragma unroll
    for (int g = 0; g < 2; g++) {
      bf16x8 pa0 = *(const bf16x8*)&sP[w][((g * 2 + 0) * 16 + l16) * PS + quad * 8];
      bf16x8 pa1 = *(const bf16x8*)&sP[w][((g * 2 + 1) * 16 + l16) * PS + quad * 8];
      #pragma unroll
      for (int dt = 0; dt < 4; dt++) {
        bf16x8 bv0 = *(const bf16x8*)&sVt[0 * 2048 + (dt * 16 + l16) * 32 + fsw];
        bf16x8 bv1 = *(const bf16x8*)&sVt[1 * 2048 + (dt * 16 + l16) * 32 + fsw];
        oacc[g][dt] = __builtin_amdgcn_mfma_f32_16x16x32_bf16(pa0, bv0, oacc[g][dt], 0, 0, 0);
        oacc[g][dt] = __builtin_amdgcn_mfma_f32_16x16x32_bf16(pa1, bv1, oacc[g][dt], 0, 0, 0);
      }
      lacc[g] = __builtin_amdgcn_mfma_f32_16x16x32_bf16(pa0, ones0, lacc[g], 0, 0, 0);
      lacc[g] = __builtin_amdgcn_mfma_f32_16x16x32_bf16(pa1, ones1, lacc[g], 0, 0, 0);
    }
  }

  // normalize + repack O through LDS -> coalesced b128 stores
  unsigned short* so = &sP[w][0];   // viewed as [32][OS]
  #pragma unroll
  for (int g = 0; g < 2; g++)
    #pragma unroll
    for (int r = 0; r < 4; r++) {
      float inv = 1.0f / lacc[g][r];
      #pragma unroll
      for (int dt = 0; dt < 4; dt++)
        so[(g * 16 + quad * 4 + r) * OS + dt * 16 + l16] = f2bf(oacc[g][dt][r] * inv);
    }
  #pragma unroll
  for (int it = 0; it < 4; it++) {
    int chunk = it * 64 + lane;           // 32 rows x 8 chunks
    int row = chunk >> 3, c8 = chunk & 7;
    int n = qt * TQ + w * 32 + row;
    if (n < SEQ)
      *(int4*)&attn[(b * SEQ + n) * CDIM + h * 64 + c8 * 8] =
          *(const int4*)&so[row * OS + c8 * 8];
  }
}

// ---------------- Proj GEMM: attn[MROWS,768] x [768,768]^T + bias, fp32 out w/ mask ----
__global__ __launch_bounds__(512, 2) void gemm_proj(
    const unsigned short* __restrict__ A,
    const unsigned short* __restrict__ Bm,
    const float* __restrict__ bias,
    float* __restrict__ out) {
  const int wg = xcd_swz(blockIdx.x, 145 * 3);
  const int mt = wg / 3, nt = wg - mt * 3;
  const int row0 = mt * 256, col0 = nt * 256;
  const int tid = threadIdx.x;

  // fully-dead output tile (all rows b>=32, all cols masked): write zeros, skip GEMM
  if (row0 >= DEAD_M && col0 >= (CDIM / 2)) {
    float4 z4 = make_float4(0.f, 0.f, 0.f, 0.f);
    #pragma unroll
    for (int it = 0; it < 32; ++it) {
      int idx = it * 512 + tid;            // 16384 float4 chunks (256 rows x 64)
      int r = idx >> 6, c4 = idx & 63;
      int m = row0 + r;
      if (m < MROWS)
        *(float4*)&out[(size_t)m * CDIM + col0 + c4 * 4] = z4;
    }
    return;
  }

  __shared__ unsigned short sL[65536];
  f32x4 acc[8][4] = {};
  gemm256_loop(A, Bm, sL, row0, col0, acc);

  const int w = tid >> 6, lane = tid & 63;
  const int quad = lane >> 4, l16 = lane & 15;
  const int wm = w >> 2, wn = w & 3;

  float bv[4];
  #pragma unroll
  for (int nf = 0; nf < 4; ++nf) bv[nf] = bias[col0 + wn * 64 + nf * 16 + l16];

  #pragma unroll
  for (int mf = 0; mf < 8; ++mf) {
    int mb = row0 + wm * 128 + mf * 16 + quad * 4;
    #pragma unroll
    for (int nf = 0; nf < 4; ++nf) {
      int col = col0 + wn * 64 + nf * 16 + l16;
      bool maskc = (col >= (CDIM / 2));
      #pragma unroll
      for (int r = 0; r < 4; ++r) {
        int m = mb + r;
        if (m < MROWS) {
          float val = acc[mf][nf][r] + bv[nf];
          if (m >= DEAD_M && maskc) val = 0.f;
          out[(size_t)m * CDIM + col] = val;
        }
      }
    }
  }
}

extern "C" void kernel_launch(void* const* d_in, const int* in_sizes, int n_in,
                              void* d_out, int out_size, void* d_ws, size_t ws_size,
                              hipStream_t stream) {
  const float* x      = (const float*)d_in[0];
  const float* qkv_w  = (const float*)d_in[1];
  const float* proj_w = (const float*)d_in[2];
  const float* proj_b = (const float*)d_in[3];
  float* out = (float*)d_out;

  size_t off = 0;
  auto alloc = [&](size_t bytes) {
    void* p = (char*)d_ws + off;
    off += (bytes + 255) & ~(size_t)255;
    return p;
  };
  const size_t XE = (size_t)MROWS * KDIM;
  unsigned short* xb   = (unsigned short*)alloc(XE * 2);
  unsigned short* wqb  = (unsigned short*)alloc((size_t)QKV_N * KDIM * 2);
  unsigned short* wpb  = (unsigned short*)alloc((size_t)CDIM * KDIM * 2);
  unsigned short* qb   = (unsigned short*)alloc(XE * 2);
  unsigned short* kb   = (unsigned short*)alloc(XE * 2);
  unsigned short* vb   = (unsigned short*)alloc(XE * 2);
  unsigned short* vtb  = (unsigned short*)alloc((size_t)BATCH * NH * HD * NPAD * 2);
  unsigned short* attnb = xb;   // xb dead after gemm_qkv
  (void)ws_size;

  cvt_bf16<<<(int)(XE / 4 / 256), 256, 0, stream>>>(x, xb, (int)(XE / 4));
  cvt_bf16<<<(QKV_N * KDIM / 4) / 256, 256, 0, stream>>>(qkv_w, wqb, QKV_N * KDIM / 4);
  cvt_bf16<<<(CDIM * KDIM / 4) / 256, 256, 0, stream>>>(proj_w, wpb, CDIM * KDIM / 4);

  gemm_qkv<<<dim3(145 * 9), 512, 0, stream>>>(xb, wqb, qb, kb, vb);

  transpose_v<<<dim3(10, BATCH * NH), 512, 0, stream>>>(vb, vtb);

  flash_attn<<<(BATCH * NH / 8) * 40, 256, 0, stream>>>(qb, kb, vtb, attnb);

  gemm_proj<<<dim3(145 * 3), 512, 0, stream>>>(attnb, wpb, proj_b, out);
}

// Round 5
// 520.810 us; speedup vs baseline: 1.3576x; 1.3576x over previous
//
#include <hip/hip_runtime.h>

// Problem constants
#define BATCH 64
#define SEQ   577
#define CDIM  768
#define NH    12
#define HD    64
#define MROWS (BATCH * SEQ)      // 36928
#define KDIM  768
#define QKV_N (3 * CDIM)         // 2304
#define NPAD  640                // vt row length (multiple of 64)
#define TQ    128                // flash q-tile rows per block
#define PS    40                 // sP row stride (u16)
#define OS    72                 // O-repack row stride (u16)
#define DEAD_M 18464             // first dead row: b>=32  (32*577)
#define DEAD_ROW0 18560          // first fully-dead 128-row tile start (145*128)

typedef short bf16x8 __attribute__((ext_vector_type(8)));
typedef float f32x4  __attribute__((ext_vector_type(4)));

__device__ __forceinline__ unsigned short f2bf(float f) {
  unsigned int u = __float_as_uint(f);
  u += 0x7fffu + ((u >> 16) & 1u);   // round-to-nearest-even
  return (unsigned short)(u >> 16);
}

__device__ __forceinline__ void async_ld16(const unsigned short* g, unsigned short* l) {
  __builtin_amdgcn_global_load_lds((const __attribute__((address_space(1))) void*)g,
                                   (__attribute__((address_space(3))) void*)l, 16, 0, 0);
}

// bijective XCD-chunked block swizzle (m204)
__device__ __forceinline__ int xcd_swz(int id, int nwg) {
  int q = nwg >> 3, r = nwg & 7;
  int xcd = id & 7, lin = id >> 3;
  int base = (xcd < r) ? xcd * (q + 1) : r * (q + 1) + (xcd - r) * q;
  return base + lin;
}

// ---------------- fp32 -> bf16 conversion ----------------
__global__ __launch_bounds__(256) void cvt_bf16(const float* __restrict__ in,
                                                unsigned short* __restrict__ out, int n4) {
  int i = blockIdx.x * 256 + threadIdx.x;
  if (i < n4) {
    float4 f = ((const float4*)in)[i];
    ushort4 o = make_ushort4(f2bf(f.x), f2bf(f.y), f2bf(f.z), f2bf(f.w));
    ((ushort4*)out)[i] = o;
  }
}

// ============================================================================
// 128x256x(BK=64) GEMM main loop, sized for 2 blocks/CU (cross-block overlap
// per m114 is the pipelining mechanism; intra-block schedule stays simple).
//   - 8 waves (2M x 4N), wave tile 64x64 (acc[4][4] = 64 VGPR)
//   - LDS: sA[128][64] (16KB) + sB[256][64] (32KB), SINGLE buffer
//   - per K-tile: barrier; stage 6 loads/thread; vmcnt0+barrier; 32 b128 reads
//     + 32 MFMA per wave
//   - 128B rows -> swizzle: 16B chunk ^= (row&7). Per-lane constant on both
//     staging source ((lane&7)^(lane>>3)) and ds_read (quad^(l16&7)); rows
//     0..7 cover all 8 bank slots once -> conflict-free (2-way on 16 rows).
// ============================================================================
__device__ __forceinline__ void gemm128x256_loop(
    const unsigned short* __restrict__ A,
    const unsigned short* __restrict__ Bm,
    unsigned short* sL,           // >= 24576 u16 (48 KiB) for the loop
    int row0, int col0,
    f32x4 (&acc)[4][4]) {
  const int tid = threadIdx.x;
  const int w = tid >> 6, lane = tid & 63;
  const int quad = lane >> 4, l16 = lane & 15;
  const int wm = w >> 2, wn = w & 3;

  // ---- staging sources: chunk id c = tid + k*512; row = c>>3, src-chunk = (c&7)^(row&7)
  const int chsw = (((lane & 7) ^ (lane >> 3)) << 3);     // elems
  int gaA0 = row0 + w * 8 + (lane >> 3);                  // A instr k=0 row
  int gaA1 = gaA0 + 64;                                   // A instr k=1 row
  if (gaA0 >= MROWS) gaA0 = MROWS - 1;
  if (gaA1 >= MROWS) gaA1 = MROWS - 1;
  const unsigned short* aS0 = A + (size_t)gaA0 * KDIM + chsw;
  const unsigned short* aS1 = A + (size_t)gaA1 * KDIM + chsw;
  const int gb = col0 + w * 8 + (lane >> 3);              // B instr k: +k*64
  const unsigned short* bS = Bm + (size_t)gb * KDIM + chsw;
  const int dstA = tid * 8;                               // u16; +4096 for k=1
  const int dstB = 8192 + tid * 8;                        // u16; +k*4096

  // ---- ds_read bases ----
  const int swzA = ((quad ^ (l16 & 7)) << 3);             // ks=0; ks=1 -> ^32
  const int arow = (wm * 64 + l16) * 64;                  // u16
  const int brow = 8192 + (wn * 64 + l16) * 64;           // u16

  #pragma unroll 2
  for (int t = 0; t < 12; ++t) {
    __syncthreads();                       // all reads of the buffer retired
    {
      const unsigned short* a0 = aS0 + t * 64;
      const unsigned short* a1 = aS1 + t * 64;
      const unsigned short* b0 = bS + t * 64;
      async_ld16(a0, sL + dstA);
      async_ld16(a1, sL + dstA + 4096);
      async_ld16(b0,                  sL + dstB);
      async_ld16(b0 + 64 * KDIM,      sL + dstB + 4096);
      async_ld16(b0 + 128 * KDIM,     sL + dstB + 8192);
      async_ld16(b0 + 192 * KDIM,     sL + dstB + 12288);
    }
    asm volatile("s_waitcnt vmcnt(0)" ::: "memory");
    __syncthreads();                       // tile t visible to all
    #pragma unroll
    for (int ks = 0; ks < 2; ++ks) {
      const int sz = swzA ^ (ks << 5);
      bf16x8 af[4], bfv[4];
      #pragma unroll
      for (int i = 0; i < 4; ++i) af[i] = *(const bf16x8*)&sL[arow + i * 1024 + sz];
      #pragma unroll
      for (int j = 0; j < 4; ++j) bfv[j] = *(const bf16x8*)&sL[brow + j * 1024 + sz];
      #pragma unroll
      for (int i = 0; i < 4; ++i)
        #pragma unroll
        for (int j = 0; j < 4; ++j)
          acc[i][j] = __builtin_amdgcn_mfma_f32_16x16x32_bf16(af[i], bfv[j], acc[i][j], 0, 0, 0);
    }
  }
}

// ---------------- QKV GEMM: [MROWS,768] x [2304,768]^T, scatter to q/k/v bf16 ----------
__global__ __launch_bounds__(512, 4) void gemm_qkv(
    const unsigned short* __restrict__ A,
    const unsigned short* __restrict__ Bm,
    unsigned short* __restrict__ qb,
    unsigned short* __restrict__ kb,
    unsigned short* __restrict__ vb) {
  const int wg = xcd_swz(blockIdx.x, 289 * 9);
  const int mt = wg / 9, nt = wg - mt * 9;
  const int row0 = mt * 128, col0 = nt * 256;
  // fully-dead tile: all rows b>=32 and all 4 col-waves h>=6  (col0%768==512)
  if (row0 >= DEAD_ROW0 && (col0 % CDIM) == 512) return;

  __shared__ unsigned short sL[32768];     // 64KB: loop uses 48KB, epilogue 64KB
  f32x4 acc[4][4] = {};
  gemm128x256_loop(A, Bm, sL, row0, col0, acc);

  __syncthreads();                         // epilogue reuses sL

  const int tid = threadIdx.x;
  const int w = tid >> 6, lane = tid & 63;
  const int quad = lane >> 4, l16 = lane & 15;
  const int wm = w >> 2, wn = w & 3;

  const int wcol = col0 + wn * 64;             // 64-aligned -> single (three, h)
  const int three = wcol / CDIM;
  const int rem = wcol - three * CDIM;
  const int h = rem >> 6;
  unsigned short* dst = (three == 0) ? qb : (three == 1) ? kb : vb;
  const float sc = (three == 0) ? 0.180336878f : 1.0f;  // 0.125 * log2(e)
  if ((row0 + wm * 64) >= DEAD_M && h >= 6) return;     // dead wave: skip stores

  // repack: wave-private 8KB region, XOR-swizzled -> conflict-free b128 reads
  unsigned short* so = sL + w * 4096;      // viewed as [64][64]
  #pragma unroll
  for (int i = 0; i < 4; ++i)
    #pragma unroll
    for (int j = 0; j < 4; ++j)
      #pragma unroll
      for (int r = 0; r < 4; ++r) {
        int rr = i * 16 + quad * 4 + r;    // 0..63 wave-local row
        so[rr * 64 + (((j * 2 + (l16 >> 3)) ^ (rr & 7)) << 3) + (l16 & 7)] =
            f2bf(acc[i][j][r] * sc);
      }
  #pragma unroll
  for (int it = 0; it < 8; ++it) {
    int c = it * 64 + lane;                // 512 int4 chunks per wave
    int rr = c >> 3, s8 = c & 7;
    int m = row0 + wm * 64 + rr;
    if (m < MROWS) {
      int b = m / SEQ, n = m - b * SEQ;
      *(int4*)&dst[((((size_t)b * NH + h) * SEQ + n) << 6) + s8 * 8] =
          *(const int4*)&so[rr * 64 + ((s8 ^ (rr & 7)) << 3)];
    }
  }
}

// ---------------- V transpose: v[bh][n][64] -> vt[bh][64][NPAD], zero pads ----------------
__global__ __launch_bounds__(512) void transpose_v(
    const unsigned short* __restrict__ v,
    unsigned short* __restrict__ vt) {
  const int bh = blockIdx.y;
  const int b = bh / NH, h = bh - b * NH;
  if (b >= 32 && h >= 6) return;
  const int t = blockIdx.x;               // 0..9
  const int tid = threadIdx.x;
  const int w = tid >> 6, lane = tid & 63; // w = d8 index 0..7
  int n = t * 64 + lane;
  bf16x8 vv = {};
  if (n < SEQ)
    vv = *(const bf16x8*)&v[(size_t)bh * (SEQ * HD) + n * HD + w * 8];
  unsigned short* dst = vt + (size_t)bh * (HD * NPAD) + (w * 8) * NPAD + t * 64 + lane;
  #pragma unroll
  for (int j = 0; j < 8; j++)
    dst[j * NPAD] = ((const unsigned short*)&vv)[j];
}

// ---------------- Flash attention (no-max softmax, MFMA row-sum) ----------------
// sK/sVt XOR-swizzled (chunk ^= (row>>1)&3): conflict-free ds_read_b128.
__global__ __launch_bounds__(256, 4) void flash_attn(
    const unsigned short* __restrict__ q,   // pre-scaled by 0.125*log2e
    const unsigned short* __restrict__ k,
    const unsigned short* __restrict__ vt,  // [BH][64][NPAD], zero-padded
    unsigned short* __restrict__ attn) {    // [B, N, C] bf16
  const int id = blockIdx.x;
  const int bh8 = id / 40;
  const int rem = id - bh8 * 40;
  const int qt = rem >> 3;
  const int bh = bh8 * 8 + (rem & 7);
  const int b = bh / NH, h = bh - b * NH;
  const int tid = threadIdx.x;
  const int w = tid >> 6, lane = tid & 63;
  const int quad = lane >> 4, l16 = lane & 15;

  if (b >= 32 && h >= 6) {
    for (int it = tid; it < TQ * 8; it += 256) {
      int r = it >> 3, c8 = (it & 7) * 8;
      int n = qt * TQ + r;
      if (n < SEQ)
        *(int4*)&attn[(b * SEQ + n) * CDIM + h * 64 + c8] = make_int4(0, 0, 0, 0);
    }
    return;
  }

  __shared__ unsigned short sK[2 * 64 * 32];    // [d-half][kv][32] (chunk-swizzled)
  __shared__ unsigned short sVt[2 * 64 * 32];   // [kv-half][d][32] (chunk-swizzled)
  __shared__ unsigned short sP[4][64 * PS];     // [wave][(g*2+hf)*16+row][PS]

  const unsigned short* qbase = q + (size_t)bh * (SEQ * HD);
  const unsigned short* kbase = k + (size_t)bh * (SEQ * HD);
  const unsigned short* vtbase = vt + (size_t)bh * (HD * NPAD);

  const int fsw = ((quad ^ ((l16 >> 1) & 3)) << 3);  // read-side swizzled chunk (u16)

  bf16x8 aq[2][2];
  #pragma unroll
  for (int g = 0; g < 2; g++) {
    int qr = qt * TQ + w * 32 + g * 16 + l16;
    if (qr > SEQ - 1) qr = SEQ - 1;
    aq[g][0] = *(const bf16x8*)&qbase[qr * HD + quad * 8];
    aq[g][1] = *(const bf16x8*)&qbase[qr * HD + 32 + quad * 8];
  }

  f32x4 oacc[2][4] = {};
  f32x4 lacc[2] = {};   // row-sum accumulator via ones-fragment MFMA

  const short ONE = (short)0x3F80;  // bf16 1.0

  for (int t = 0; t < 10; t++) {
    __syncthreads();
    #pragma unroll
    for (int c = 0; c < 2; c++) {
      int rI = tid >> 2;
      int c4s = (tid & 3) ^ ((tid >> 3) & 3);   // source chunk pre-swizzle
      int base = c * 2048 + (tid & ~63) * 8;
      int kr = t * 64 + rI; if (kr > SEQ - 1) kr = SEQ - 1;
      async_ld16(kbase + kr * HD + c * 32 + c4s * 8, sK + base);
      async_ld16(vtbase + rI * NPAD + t * 64 + c * 32 + c4s * 8, sVt + base);
    }
    __syncthreads();

    bf16x8 bk[4][2];
    #pragma unroll
    for (int nt = 0; nt < 4; nt++) {
      bk[nt][0] = *(const bf16x8*)&sK[0 * 2048 + (nt * 16 + l16) * 32 + fsw];
      bk[nt][1] = *(const bf16x8*)&sK[1 * 2048 + (nt * 16 + l16) * 32 + fsw];
    }

    // ones B-fragment: B[n][k]=1 for valid kv, else 0
    bf16x8 ones0, ones1;
    if (t < 9) {
      #pragma unroll
      for (int j = 0; j < 8; j++) { ones0[j] = ONE; ones1[j] = ONE; }
    } else {
      bf16x8 z = {};
      ones0 = z; ones1 = z;
      ones0[0] = (quad == 0) ? ONE : (short)0;   // only kv==576 valid
    }

    #pragma unroll
    for (int g = 0; g < 2; g++) {
      f32x4 s[4];
      #pragma unroll
      for (int nt = 0; nt < 4; nt++) {
        f32x4 z = {};
        z = __builtin_amdgcn_mfma_f32_16x16x32_bf16(aq[g][0], bk[nt][0], z, 0, 0, 0);
        z = __builtin_amdgcn_mfma_f32_16x16x32_bf16(aq[g][1], bk[nt][1], z, 0, 0, 0);
        s[nt] = z;
      }
      #pragma unroll
      for (int nt = 0; nt < 4; nt++)
        #pragma unroll
        for (int r = 0; r < 4; r++)
          sP[w][((g * 2 + (nt >> 1)) * 16 + quad * 4 + r) * PS + (nt & 1) * 16 + l16] =
              f2bf(__builtin_exp2f(s[nt][r]));
    }

    // PV + row-sum (sP wave-private; same-wave DS ordering suffices, no barrier)
    #pragma unroll
    for (int g = 0; g < 2; g++) {
      bf16x8 pa0 = *(const bf16x8*)&sP[w][((g * 2 + 0) * 16 + l16) * PS + quad * 8];
      bf16x8 pa1 = *(const bf16x8*)&sP[w][((g * 2 + 1) * 16 + l16) * PS + quad * 8];
      #pragma unroll
      for (int dt = 0; dt < 4; dt++) {
        bf16x8 bv0 = *(const bf16x8*)&sVt[0 * 2048 + (dt * 16 + l16) * 32 + fsw];
        bf16x8 bv1 = *(const bf16x8*)&sVt[1 * 2048 + (dt * 16 + l16) * 32 + fsw];
        oacc[g][dt] = __builtin_amdgcn_mfma_f32_16x16x32_bf16(pa0, bv0, oacc[g][dt], 0, 0, 0);
        oacc[g][dt] = __builtin_amdgcn_mfma_f32_16x16x32_bf16(pa1, bv1, oacc[g][dt], 0, 0, 0);
      }
      lacc[g] = __builtin_amdgcn_mfma_f32_16x16x32_bf16(pa0, ones0, lacc[g], 0, 0, 0);
      lacc[g] = __builtin_amdgcn_mfma_f32_16x16x32_bf16(pa1, ones1, lacc[g], 0, 0, 0);
    }
  }

  // normalize + repack O through LDS -> coalesced b128 stores
  unsigned short* so = &sP[w][0];   // viewed as [32][OS]
  #pragma unroll
  for (int g = 0; g < 2; g++)
    #pragma unroll
    for (int r = 0; r < 4; r++) {
      float inv = 1.0f / lacc[g][r];
      #pragma unroll
      for (int dt = 0; dt < 4; dt++)
        so[(g * 16 + quad * 4 + r) * OS + dt * 16 + l16] = f2bf(oacc[g][dt][r] * inv);
    }
  #pragma unroll
  for (int it = 0; it < 4; it++) {
    int chunk = it * 64 + lane;           // 32 rows x 8 chunks
    int row = chunk >> 3, c8 = chunk & 7;
    int n = qt * TQ + w * 32 + row;
    if (n < SEQ)
      *(int4*)&attn[(b * SEQ + n) * CDIM + h * 64 + c8 * 8] =
          *(const int4*)&so[row * OS + c8 * 8];
  }
}

// ---------------- Proj GEMM: attn[MROWS,768] x [768,768]^T + bias, fp32 out w/ mask ----
__global__ __launch_bounds__(512, 4) void gemm_proj(
    const unsigned short* __restrict__ A,
    const unsigned short* __restrict__ Bm,
    const float* __restrict__ bias,
    float* __restrict__ out) {
  const int wg = xcd_swz(blockIdx.x, 289 * 3);
  const int mt = wg / 3, nt = wg - mt * 3;
  const int row0 = mt * 128, col0 = nt * 256;
  const int tid = threadIdx.x;

  // fully-dead output tile (all rows b>=32, all cols masked): write zeros, skip GEMM
  if (row0 >= DEAD_ROW0 && col0 >= (CDIM / 2)) {
    float4 z4 = make_float4(0.f, 0.f, 0.f, 0.f);
    #pragma unroll
    for (int it = 0; it < 16; ++it) {
      int idx = it * 512 + tid;            // 8192 float4 chunks (128 rows x 64)
      int r = idx >> 6, c4 = idx & 63;
      int m = row0 + r;
      if (m < MROWS)
        *(float4*)&out[(size_t)m * CDIM + col0 + c4 * 4] = z4;
    }
    return;
  }

  __shared__ unsigned short sL[24576];     // 48KB
  f32x4 acc[4][4] = {};
  gemm128x256_loop(A, Bm, sL, row0, col0, acc);

  const int w = tid >> 6, lane = tid & 63;
  const int quad = lane >> 4, l16 = lane & 15;
  const int wm = w >> 2, wn = w & 3;

  float bv[4];
  #pragma unroll
  for (int nf = 0; nf < 4; ++nf) bv[nf] = bias[col0 + wn * 64 + nf * 16 + l16];

  #pragma unroll
  for (int mf = 0; mf < 4; ++mf) {
    int mb = row0 + wm * 64 + mf * 16 + quad * 4;
    #pragma unroll
    for (int nf = 0; nf < 4; ++nf) {
      int col = col0 + wn * 64 + nf * 16 + l16;
      bool maskc = (col >= (CDIM / 2));
      #pragma unroll
      for (int r = 0; r < 4; ++r) {
        int m = mb + r;
        if (m < MROWS) {
          float val = acc[mf][nf][r] + bv[nf];
          if (m >= DEAD_M && maskc) val = 0.f;
          out[(size_t)m * CDIM + col] = val;
        }
      }
    }
  }
}

extern "C" void kernel_launch(void* const* d_in, const int* in_sizes, int n_in,
                              void* d_out, int out_size, void* d_ws, size_t ws_size,
                              hipStream_t stream) {
  const float* x      = (const float*)d_in[0];
  const float* qkv_w  = (const float*)d_in[1];
  const float* proj_w = (const float*)d_in[2];
  const float* proj_b = (const float*)d_in[3];
  float* out = (float*)d_out;

  size_t off = 0;
  auto alloc = [&](size_t bytes) {
    void* p = (char*)d_ws + off;
    off += (bytes + 255) & ~(size_t)255;
    return p;
  };
  const size_t XE = (size_t)MROWS * KDIM;
  unsigned short* xb   = (unsigned short*)alloc(XE * 2);
  unsigned short* wqb  = (unsigned short*)alloc((size_t)QKV_N * KDIM * 2);
  unsigned short* wpb  = (unsigned short*)alloc((size_t)CDIM * KDIM * 2);
  unsigned short* qb   = (unsigned short*)alloc(XE * 2);
  unsigned short* kb   = (unsigned short*)alloc(XE * 2);
  unsigned short* vb   = (unsigned short*)alloc(XE * 2);
  unsigned short* vtb  = (unsigned short*)alloc((size_t)BATCH * NH * HD * NPAD * 2);
  unsigned short* attnb = xb;   // xb dead after gemm_qkv
  (void)ws_size;

  cvt_bf16<<<(int)(XE / 4 / 256), 256, 0, stream>>>(x, xb, (int)(XE / 4));
  cvt_bf16<<<(QKV_N * KDIM / 4) / 256, 256, 0, stream>>>(qkv_w, wqb, QKV_N * KDIM / 4);
  cvt_bf16<<<(CDIM * KDIM / 4) / 256, 256, 0, stream>>>(proj_w, wpb, CDIM * KDIM / 4);

  gemm_qkv<<<dim3(289 * 9), 512, 0, stream>>>(xb, wqb, qb, kb, vb);

  transpose_v<<<dim3(10, BATCH * NH), 512, 0, stream>>>(vb, vtb);

  flash_attn<<<(BATCH * NH / 8) * 40, 256, 0, stream>>>(qb, kb, vtb, attnb);

  gemm_proj<<<dim3(289 * 3), 512, 0, stream>>>(attnb, wpb, proj_b, out);
}